// Round 16
// baseline (161.107 us; speedup 1.0000x reference)
//
#include <hip/hip_runtime.h>
#include <hip/hip_bf16.h>

#define NPIX 2304      // 48*48
#define HW 48
#define CDIM 256
#define NHEADS 8
#define HD 32
#define SCALE_CONST 0.17677669529663687f   // 32^-0.5
#define LOG2E 1.4426950408889634f

typedef __attribute__((ext_vector_type(8))) short  short8v;
typedef __attribute__((ext_vector_type(4))) short  short4v;
typedef __attribute__((ext_vector_type(4))) float  floatx4;

__device__ inline short f2bf(float f) {
    unsigned u = __builtin_bit_cast(unsigned, f);
    u += 0x7FFFu + ((u >> 16) & 1u);       // round-to-nearest-even
    return (short)(u >> 16);
}
__device__ inline float bf2f(unsigned short us) {
    return __builtin_bit_cast(float, (unsigned)us << 16);
}
__device__ inline float fexp2(float x) {
    return __builtin_amdgcn_exp2f(x);      // v_exp_f32 (base-2 native)
}

// ---------------------------------------------------------------------------
// Prep: blocks 0..575 transpose+cast x -> XT[b][n][256] bf16;
//       blocks 576..639 convert weights fp32->bf16.
// ---------------------------------------------------------------------------
__global__ __launch_bounds__(256) void prep_kernel(
    const float* __restrict__ x,     // [B][256][NPIX]
    short* __restrict__ XT,          // [B][NPIX][256]
    const float* __restrict__ wqk, const float* __restrict__ wv,
    const float* __restrict__ wp,
    short* __restrict__ wqkb, short* __restrict__ wvb, short* __restrict__ wpb)
{
    const int bx = blockIdx.x;
    const int t = threadIdx.x;
    if (bx >= 576) {
        int tid = (bx - 576) * 256 + t;
        for (int idx = tid; idx < 262144; idx += 16384) {
            if (idx < 131072)       wqkb[idx] = f2bf(wqk[idx]);
            else if (idx < 196608)  wvb[idx - 131072] = f2bf(wv[idx - 131072]);
            else                    wpb[idx - 196608] = f2bf(wp[idx - 196608]);
        }
        return;
    }
    __shared__ float sT[64][65];
    const int nt = bx % 36, ct = (bx / 36) & 3, b = bx / 144;
    const int c0 = ct * 64, n0 = nt * 64;
    const float* sp = x + ((size_t)b * 256 + c0) * NPIX + n0;
    const int cl = t >> 6, n = t & 63;
#pragma unroll
    for (int it = 0; it < 16; ++it) {
        int c = it * 4 + cl;
        sT[n][c] = sp[(size_t)c * NPIX + n];
    }
    __syncthreads();
    const int nr = t >> 2, q = t & 3;
    short out[16];
#pragma unroll
    for (int j = 0; j < 16; ++j) out[j] = f2bf(sT[nr][q * 16 + j]);
    short* dp = XT + ((size_t)b * NPIX + n0 + nr) * 256 + c0 + q * 16;
    *(int4*)dp = *(int4*)out;
    *(int4*)(dp + 8) = *(int4*)(out + 8);
}

// ---------------------------------------------------------------------------
// Fused QK+V conv (MFMA). Grid y in [0,6): block handles og = y and y+6.
// ---------------------------------------------------------------------------
#define XROW 528   // bytes per LDS row (512 + 16 pad)

__device__ inline void stage_xt_tile(const short* __restrict__ src_base,
                                     char* __restrict__ sX, int t)
{
    const short* src = src_base + (size_t)(t >> 3) * 256 + (t & 7) * 32;
    char* dst = sX + (t >> 3) * XROW + (t & 7) * 64;
#pragma unroll
    for (int rr = 0; rr < 2; ++rr) {
        const short* s = src + rr * 32 * 256;
        char* d = dst + rr * 32 * XROW;
        *(int4*)d        = *(const int4*)s;
        *(int4*)(d + 16) = *(const int4*)(s + 8);
        *(int4*)(d + 32) = *(const int4*)(s + 16);
        *(int4*)(d + 48) = *(const int4*)(s + 24);
    }
}

__global__ __launch_bounds__(256) void conv_qkv_mfma(
    const short* __restrict__ Wqk,   // [512][256] bf16
    const short* __restrict__ Wv,    // [256][256] bf16
    const float* __restrict__ bqk,   // [512]
    const float* __restrict__ bv,    // [256]
    const short* __restrict__ XT,    // [B][NPIX][256] bf16
    short* __restrict__ QT,          // [B*8][NPIX][32]
    short* __restrict__ KT,          // [B*8][NPIX][32]
    short* __restrict__ VB)          // [B][256][NPIX]
{
    __shared__ __align__(16) char sX[64 * XROW];
    const int n0 = blockIdx.x * 64;
    const int b  = blockIdx.z;
    const int t = threadIdx.x, lane = t & 63, w = t >> 6;
    const int l15 = lane & 15, quad = lane >> 4;

    stage_xt_tile(XT + ((size_t)b * NPIX + n0) * 256, sX, t);
    __syncthreads();

    floatx4 accs[2][4];
#pragma unroll
    for (int g = 0; g < 2; ++g) {
        const int og = blockIdx.y + g * 6;
        const bool isV = (og >= 8);
        const short* Wb = isV ? Wv + (size_t)((og - 8) * 64 + w * 16 + l15) * CDIM
                              : Wqk + (size_t)(og * 64 + w * 16 + l15) * CDIM;
#pragma unroll
        for (int ib = 0; ib < 4; ++ib) accs[g][ib] = (floatx4){0.f, 0.f, 0.f, 0.f};
#pragma unroll
        for (int s = 0; s < 8; ++s) {
            short8v af = *(const short8v*)(Wb + s * 32 + quad * 8);
#pragma unroll
            for (int ib = 0; ib < 4; ++ib) {
                short8v bf = *(const short8v*)(sX + (ib * 16 + l15) * XROW + s * 64 + quad * 16);
                accs[g][ib] = __builtin_amdgcn_mfma_f32_16x16x32_bf16(af, bf, accs[g][ib], 0, 0, 0);
            }
        }
    }

#pragma unroll
    for (int g = 0; g < 2; ++g) {
        const int og = blockIdx.y + g * 6;
        const bool isV = (og >= 8);
        __syncthreads();   // sX free (MFMA reads / prior store-reads done)
        if (!isV) {
            const bool isQ = (w < 2);
            const float scl = isQ ? SCALE_CONST * LOG2E : 1.0f;
            float bvv[4];
#pragma unroll
            for (int r = 0; r < 4; ++r) bvv[r] = bqk[og * 64 + w * 16 + quad * 4 + r];
#pragma unroll
            for (int ib = 0; ib < 4; ++ib) {
                short pb[4];
#pragma unroll
                for (int r = 0; r < 4; ++r) pb[r] = f2bf((accs[g][ib][r] + bvv[r]) * scl);
                *(short4v*)(sX + (ib * 16 + l15) * 136 + (w * 16 + quad * 4) * 2) = *(short4v*)pb;
            }
            __syncthreads();
            const int n = t >> 2, q = t & 3;
            int4 v0 = *(const int4*)(sX + n * 136 + q * 32);
            int4 v1 = *(const int4*)(sX + n * 136 + q * 32 + 16);
            short* dst = ((q < 2) ? QT : KT)
                       + ((size_t)(b * 8 + og) * NPIX + n0 + n) * HD + (q & 1) * 16;
            *(int4*)dst = v0;
            *(int4*)(dst + 8) = v1;
        } else {
            const int o0 = (og - 8) * 64 + w * 16 + quad * 4;
            float bvv[4];
#pragma unroll
            for (int r = 0; r < 4; ++r) bvv[r] = bv[o0 + r];
#pragma unroll
            for (int ib = 0; ib < 4; ++ib) {
                short pb[4];
#pragma unroll
                for (int r = 0; r < 4; ++r) pb[r] = f2bf(accs[g][ib][r] + bvv[r]);
                *(short4v*)(sX + (ib * 16 + l15) * 132 + (w * 16 + quad * 4) * 2) = *(short4v*)pb;
            }
            __syncthreads();
            const int o = t >> 2, q = t & 3;
            short tmp[16];
#pragma unroll
            for (int k = 0; k < 16; ++k)
                tmp[k] = *(const short*)(sX + (q * 16 + k) * 132 + o * 2);
            short* dst = VB + ((size_t)b * 256 + (og - 8) * 64 + o) * NPIX + n0 + q * 16;
            *(int4*)dst = *(int4*)tmp;
            *(int4*)(dst + 8) = *(int4*)(tmp + 8);
        }
    }
}

// ---------------------------------------------------------------------------
// Flash attention, TWO query-tiles per block (shared K/V sweep) + fused
// depthwise-3x3 PE epilogue. XCD swizzle: hh = blockIdx & 7.
// Items A (i0) and B (i0+64) give in-wave ILP: exp(A) overlaps MFMA(B);
// K/V fragments read once, used by both items.
// ---------------------------------------------------------------------------
#define KROW 72
#define VROW 136
#define PROW 136
#define SK0 0                    // 64*72 = 4608
#define SK1 4608
#define SV0 9216                 // 32*136 = 4352
#define SV1 13568
#define SP0 17920                // 2 items * 4 waves * 16 * 136 = 17408
#define FL_SMEM 35328
#define DROW2 248                // halo row stride in shorts (496B, 16B mult)

__global__ __launch_bounds__(256) void flash_attn_mfma(
    const short* __restrict__ QT,   // [bh][i][32] bf16, scaled by SCALE*LOG2E
    const short* __restrict__ KT,   // [bh][j][32] bf16
    const short* __restrict__ VB,   // [b][256][NPIX] bf16
    const float* __restrict__ w_pe, // [256][9] fp32
    const float* __restrict__ b_pe, // [256]
    short* __restrict__ ST)         // [b][NPIX][256] bf16 (= attn/l + pe)^T
{
    __shared__ __align__(16) char smem[FL_SMEM];

    // ---- XCD-aware decode: grid = 576 1-D; block owns i-tiles i0A, i0A+64
    const int hh   = blockIdx.x & 7;
    const int slot = blockIdx.x >> 3;         // 0..71
    const int b    = slot / 18;
    const int i0A  = (slot % 18) * 128;
    const int bh   = b * 8 + hh;

    const short* KTp = KT + (size_t)bh * NPIX * HD;
    const short* Vp  = VB + (size_t)(b * 256 + hh * HD) * NPIX;

    const int t    = threadIdx.x;
    const int lane = t & 63;
    const int w    = t >> 6;
    const int l15  = lane & 15;
    const int quad = lane >> 4;

    const short8v qfragA = *(const short8v*)(
        QT + ((size_t)bh * NPIX + i0A + w * 16 + l15) * HD + quad * 8);
    const short8v qfragB = *(const short8v*)(
        QT + ((size_t)bh * NPIX + i0A + 64 + w * 16 + l15) * HD + quad * 8);

    short8v ones;
#pragma unroll
    for (int k = 0; k < 8; ++k) ones[k] = (short)0x3F80;   // bf16 1.0

    char* const sPwA = smem + SP0 + w * (16 * PROW);
    char* const sPwB = smem + SP0 + (4 + w) * (16 * PROW);

    floatx4 oaccA[2], oaccB[2], laccA, laccB;
    oaccA[0] = (floatx4){0.f, 0.f, 0.f, 0.f};
    oaccA[1] = (floatx4){0.f, 0.f, 0.f, 0.f};
    oaccB[0] = oaccA[0]; oaccB[1] = oaccA[0];
    laccA = oaccA[0]; laccB = oaccA[0];

    const short* ksrc = KTp + (size_t)(t >> 2) * HD + (t & 3) * 8;
    const short* vsrc = Vp + (size_t)(t >> 3) * NPIX + (t & 7) * 8;
    const int koff = (t >> 2) * KROW + (t & 3) * 16;
    const int voff = (t >> 3) * VROW + (t & 7) * 16;

    int4 kst = *(const int4*)ksrc;
    int4 vst = *(const int4*)vsrc;

    for (int it = 0; it < 36; ++it) {
        char* bufK = smem + ((it & 1) ? SK1 : SK0);
        char* bufV = smem + ((it & 1) ? SV1 : SV0);
        *(int2*)(bufK + koff)     = *(int2*)&kst;
        *(int2*)(bufK + koff + 8) = *((int2*)&kst + 1);
        *(int2*)(bufV + voff)     = *(int2*)&vst;
        *(int2*)(bufV + voff + 8) = *((int2*)&vst + 1);
        if (it + 1 < 36) {
            kst = *(const int4*)(ksrc + (size_t)(it + 1) * 64 * HD);
            vst = *(const int4*)(vsrc + (it + 1) * 64);
        }
        __syncthreads();

        // ---- S' = K Q^T for both items; K fragment read once ----
        floatx4 sA[4], sB[4];
#pragma unroll
        for (int jb = 0; jb < 4; ++jb) {
            const char* ka = bufK + (jb * 16 + l15) * KROW + quad * 16;
            short8v af;
            ((int2*)&af)[0] = *(const int2*)ka;
            ((int2*)&af)[1] = *(const int2*)(ka + 8);
            sA[jb] = __builtin_amdgcn_mfma_f32_16x16x32_bf16(
                af, qfragA, (floatx4){0.f, 0.f, 0.f, 0.f}, 0, 0, 0);
            sB[jb] = __builtin_amdgcn_mfma_f32_16x16x32_bf16(
                af, qfragB, (floatx4){0.f, 0.f, 0.f, 0.f}, 0, 0, 0);
        }

        // ---- exp2(s) raw, pack bf16 P via v_perm (A then B) ----
#pragma unroll
        for (int jb = 0; jb < 4; ++jb) {
            unsigned ta[4], tb[4];
#pragma unroll
            for (int r = 0; r < 4; ++r) {
                ta[r] = __builtin_bit_cast(unsigned, fexp2(sA[jb][r]));
                tb[r] = __builtin_bit_cast(unsigned, fexp2(sB[jb][r]));
            }
            int2 pwa, pwb;
            pwa.x = (int)__builtin_amdgcn_perm(ta[1], ta[0], 0x07060302u);
            pwa.y = (int)__builtin_amdgcn_perm(ta[3], ta[2], 0x07060302u);
            pwb.x = (int)__builtin_amdgcn_perm(tb[1], tb[0], 0x07060302u);
            pwb.y = (int)__builtin_amdgcn_perm(tb[3], tb[2], 0x07060302u);
            *(int2*)(sPwA + l15 * PROW + jb * 32 + quad * 8) = pwa;
            *(int2*)(sPwB + l15 * PROW + jb * 32 + quad * 8) = pwb;
        }

        // ---- PV both items; V fragment read once ----
#pragma unroll
        for (int ks = 0; ks < 2; ++ks) {
            const char* paA = sPwA + l15 * PROW + ks * 64 + quad * 16;
            const char* paB = sPwB + l15 * PROW + ks * 64 + quad * 16;
            short8v pfA, pfB;
            ((int2*)&pfA)[0] = *(const int2*)paA;
            ((int2*)&pfA)[1] = *(const int2*)(paA + 8);
            ((int2*)&pfB)[0] = *(const int2*)paB;
            ((int2*)&pfB)[1] = *(const int2*)(paB + 8);
#pragma unroll
            for (int db = 0; db < 2; ++db) {
                const char* va = bufV + (db * 16 + l15) * VROW + ks * 64 + quad * 16;
                short8v vf;
                ((int2*)&vf)[0] = *(const int2*)va;
                ((int2*)&vf)[1] = *(const int2*)(va + 8);
                oaccA[db] = __builtin_amdgcn_mfma_f32_16x16x32_bf16(vf, pfA, oaccA[db], 0, 0, 0);
                oaccB[db] = __builtin_amdgcn_mfma_f32_16x16x32_bf16(vf, pfB, oaccB[db], 0, 0, 0);
            }
            laccA = __builtin_amdgcn_mfma_f32_16x16x32_bf16(ones, pfA, laccA, 0, 0, 0);
            laccB = __builtin_amdgcn_mfma_f32_16x16x32_bf16(ones, pfB, laccB, 0, 0, 0);
        }
    }

    // ================= epilogue: fused depthwise-3x3 PE =================
    const float invlA = 1.0f / laccA[0];
    const float invlB = 1.0f / laccB[0];
    __syncthreads();   // all waves past final P/V LDS reads; smem free

    short* const sO    = (short*)smem;            // [128 px][36 shorts]
    short* const sHalo = (short*)(smem + 9216);   // [32 ch][248 shorts]

    // O (attn/l) -> LDS bf16, both items, MFMA C-layout -> [px][d]
    {
        const int il = w * 16 + l15;
#pragma unroll
        for (int db = 0; db < 2; ++db) {
            short obA[4], obB[4];
#pragma unroll
            for (int r = 0; r < 4; ++r) {
                obA[r] = f2bf(oaccA[db][r] * invlA);
                obB[r] = f2bf(oaccB[db][r] * invlB);
            }
            *(short4v*)(sO + il * 36 + db * 16 + quad * 4) = *(short4v*)obA;
            *(short4v*)(sO + (64 + il) * 36 + db * 16 + quad * 4) = *(short4v*)obB;
        }
    }
    // VB halo: 32 ch x 232 px window [i0A-52, i0A+180), zero-filled off-plane
    for (int ch8 = t; ch8 < 928; ch8 += 256) {
        int ch = ch8 / 29, off = (ch8 % 29) * 8;
        int base = i0A - 52 + off;
        const short* src = VB + ((size_t)b * 256 + hh * HD + ch) * NPIX;
        short tmp[8];
        if (base >= 0 && base + 8 <= NPIX) {
            *(int4*)tmp = *(const int4*)(src + base);
        } else {
#pragma unroll
            for (int u = 0; u < 8; ++u) {
                int p = base + u;
                tmp[u] = (p >= 0 && p < NPIX) ? src[p] : (short)0;
            }
        }
        *(int4*)&sHalo[ch * DROW2 + off] = *(int4*)tmp;
    }
    __syncthreads();

    // one channel per lane: d = t&31 (9 weights/thread), 8 px per item
    {
        const int d  = t & 31;
        const int pg = t >> 5;
        const int c  = hh * HD + d;
        float wv[9];
#pragma unroll
        for (int k = 0; k < 9; ++k) wv[k] = w_pe[c * 9 + k];
        const float bb = b_pe[c];

#pragma unroll
        for (int item = 0; item < 2; ++item) {
            const int px0  = i0A + item * 64 + pg * 8;
            const int col0 = px0 % HW;
            const short* sprow = &sHalo[d * DROW2 + 52 + item * 64 + pg * 8];
            short* stp = ST + ((size_t)b * NPIX + px0) * 256 + c;
#pragma unroll
            for (int u = 0; u < 8; ++u) {
                int colu = col0 + u; if (colu >= HW) colu -= HW;
                const bool okL = (colu != 0), okR = (colu != HW - 1);
                float a = bb;
#pragma unroll
                for (int dy = 0; dy < 3; ++dy) {
                    int ci = u + (dy - 1) * HW;
                    a += wv[dy * 3 + 1] * bf2f((unsigned short)sprow[ci]);
                    if (okL) a += wv[dy * 3 + 0] * bf2f((unsigned short)sprow[ci - 1]);
                    if (okR) a += wv[dy * 3 + 2] * bf2f((unsigned short)sprow[ci + 1]);
                }
                float o = bf2f((unsigned short)sO[(item * 64 + pg * 8 + u) * 36 + d]);
                stp[(size_t)u * 256] = f2bf(o + a);
            }
        }
    }
}

// ---------------------------------------------------------------------------
// Proj conv (MFMA); output repacked through LDS for coalesced fp32 stores.
// ---------------------------------------------------------------------------
__global__ __launch_bounds__(256) void conv_proj_mfma(
    const short* __restrict__ Wb,    // [256][256] bf16
    const float* __restrict__ bias,
    const short* __restrict__ ST,    // [B][NPIX][256] bf16
    float* __restrict__ out)
{
    __shared__ __align__(16) char sX[64 * XROW];
    const int n0 = blockIdx.x * 64;
    const int og = blockIdx.y;
    const int b  = blockIdx.z;
    const int t = threadIdx.x, lane = t & 63, w = t >> 6;
    const int l15 = lane & 15, quad = lane >> 4;

    stage_xt_tile(ST + ((size_t)b * NPIX + n0) * 256, sX, t);
    __syncthreads();

    const short* Arow = Wb + (size_t)(og * 64 + w * 16 + l15) * CDIM;
    floatx4 acc[4];
#pragma unroll
    for (int ib = 0; ib < 4; ++ib) acc[ib] = (floatx4){0.f, 0.f, 0.f, 0.f};
#pragma unroll
    for (int s = 0; s < 8; ++s) {
        short8v af = *(const short8v*)(Arow + s * 32 + quad * 8);
#pragma unroll
        for (int ib = 0; ib < 4; ++ib) {
            short8v bf = *(const short8v*)(sX + (ib * 16 + l15) * XROW + s * 64 + quad * 16);
            acc[ib] = __builtin_amdgcn_mfma_f32_16x16x32_bf16(af, bf, acc[ib], 0, 0, 0);
        }
    }
    __syncthreads();   // sX reusable: repack [o][64 n] fp32, rows 272B

    {
        float bvv[4];
#pragma unroll
        for (int r = 0; r < 4; ++r) bvv[r] = bias[og * 64 + w * 16 + quad * 4 + r];
        float* sRep = (float*)sX;
#pragma unroll
        for (int r = 0; r < 4; ++r)
#pragma unroll
            for (int ib = 0; ib < 4; ++ib)
                sRep[(w * 16 + quad * 4 + r) * 68 + ib * 16 + l15] = acc[ib][r] + bvv[r];
    }
    __syncthreads();

    const int o = t >> 2, q = t & 3;
    const float* src = (const float*)sX + o * 68 + q * 16;
    float* dst = out + ((size_t)b * 256 + og * 64 + o) * NPIX + n0 + q * 16;
#pragma unroll
    for (int k = 0; k < 4; ++k)
        *(int4*)(dst + k * 4) = *(const int4*)(src + k * 4);
}

// ---------------------------------------------------------------------------
extern "C" void kernel_launch(void* const* d_in, const int* in_sizes, int n_in,
                              void* d_out, int out_size, void* d_ws, size_t ws_size,
                              hipStream_t stream) {
    const float* x      = (const float*)d_in[0];
    const float* w_qk   = (const float*)d_in[1];
    const float* b_qk   = (const float*)d_in[2];
    const float* w_v    = (const float*)d_in[3];
    const float* b_v    = (const float*)d_in[4];
    const float* w_pe   = (const float*)d_in[5];
    const float* b_pe   = (const float*)d_in[6];
    const float* w_proj = (const float*)d_in[7];
    const float* b_proj = (const float*)d_in[8];
    float* out = (float*)d_out;

    char* wsb = (char*)d_ws;
    short* ws_xt  = (short*)wsb;  wsb += (size_t)4 * NPIX * 256 * 2;   // XT bf16
    short* ws_qt  = (short*)wsb;  wsb += (size_t)32 * NPIX * HD * 2;   // QT bf16
    short* ws_kt  = (short*)wsb;  wsb += (size_t)32 * NPIX * HD * 2;   // KT bf16
    short* ws_vb  = (short*)wsb;  wsb += (size_t)4 * 256 * NPIX * 2;   // VB bf16
    short* ws_st  = (short*)wsb;  wsb += (size_t)4 * NPIX * 256 * 2;   // ST bf16
    short* ws_wqk = (short*)wsb;  wsb += (size_t)512 * 256 * 2;
    short* ws_wv  = (short*)wsb;  wsb += (size_t)256 * 256 * 2;
    short* ws_wp  = (short*)wsb;  wsb += (size_t)256 * 256 * 2;

    prep_kernel<<<dim3(640), 256, 0, stream>>>(x, ws_xt, w_qk, w_v, w_proj,
                                               ws_wqk, ws_wv, ws_wp);
    conv_qkv_mfma<<<dim3(36, 6, 4), 256, 0, stream>>>(ws_wqk, ws_wv, b_qk, b_v,
                                                      ws_xt, ws_qt, ws_kt, ws_vb);
    flash_attn_mfma<<<dim3(576), 256, 0, stream>>>(ws_qt, ws_kt, ws_vb,
                                                   w_pe, b_pe, ws_st);
    conv_proj_mfma<<<dim3(36, 4, 4), 256, 0, stream>>>(ws_wp, b_proj, ws_st, out);
}

// Round 17
// 157.695 us; speedup vs baseline: 1.0216x; 1.0216x over previous
//
#include <hip/hip_runtime.h>
#include <hip/hip_bf16.h>

#define NPIX 2304      // 48*48
#define HW 48
#define CDIM 256
#define NHEADS 8
#define HD 32
#define SCALE_CONST 0.17677669529663687f   // 32^-0.5
#define LOG2E 1.4426950408889634f

typedef __attribute__((ext_vector_type(8))) short  short8v;
typedef __attribute__((ext_vector_type(4))) short  short4v;
typedef __attribute__((ext_vector_type(4))) float  floatx4;

__device__ inline short f2bf(float f) {
    unsigned u = __builtin_bit_cast(unsigned, f);
    u += 0x7FFFu + ((u >> 16) & 1u);       // round-to-nearest-even
    return (short)(u >> 16);
}
__device__ inline float bf2f(unsigned short us) {
    return __builtin_bit_cast(float, (unsigned)us << 16);
}
__device__ inline float fexp2(float x) {
    return __builtin_amdgcn_exp2f(x);      // v_exp_f32 (base-2 native)
}

// ---------------------------------------------------------------------------
// Prep: blocks 0..575 transpose+cast x -> XT[b][n][256] bf16;
//       blocks 576..639 convert weights fp32->bf16.
// ---------------------------------------------------------------------------
__global__ __launch_bounds__(256) void prep_kernel(
    const float* __restrict__ x,     // [B][256][NPIX]
    short* __restrict__ XT,          // [B][NPIX][256]
    const float* __restrict__ wqk, const float* __restrict__ wv,
    const float* __restrict__ wp,
    short* __restrict__ wqkb, short* __restrict__ wvb, short* __restrict__ wpb)
{
    const int bx = blockIdx.x;
    const int t = threadIdx.x;
    if (bx >= 576) {
        int tid = (bx - 576) * 256 + t;
        for (int idx = tid; idx < 262144; idx += 16384) {
            if (idx < 131072)       wqkb[idx] = f2bf(wqk[idx]);
            else if (idx < 196608)  wvb[idx - 131072] = f2bf(wv[idx - 131072]);
            else                    wpb[idx - 196608] = f2bf(wp[idx - 196608]);
        }
        return;
    }
    __shared__ float sT[64][65];
    const int nt = bx % 36, ct = (bx / 36) & 3, b = bx / 144;
    const int c0 = ct * 64, n0 = nt * 64;
    const float* sp = x + ((size_t)b * 256 + c0) * NPIX + n0;
    const int cl = t >> 6, n = t & 63;
#pragma unroll
    for (int it = 0; it < 16; ++it) {
        int c = it * 4 + cl;
        sT[n][c] = sp[(size_t)c * NPIX + n];
    }
    __syncthreads();
    const int nr = t >> 2, q = t & 3;
    short out[16];
#pragma unroll
    for (int j = 0; j < 16; ++j) out[j] = f2bf(sT[nr][q * 16 + j]);
    short* dp = XT + ((size_t)b * NPIX + n0 + nr) * 256 + c0 + q * 16;
    *(int4*)dp = *(int4*)out;
    *(int4*)(dp + 8) = *(int4*)(out + 8);
}

// ---------------------------------------------------------------------------
// Fused QK+V conv (MFMA). 1-D grid 864 with XCD affinity: all 6 og-blocks of
// a pixel-tile T land on XCD T%8 so the XT tile is fetched into ONE L2.
// Block handles og = yy and yy+6. og 0..7 = QK head h; 8..11 = V row-group.
// ---------------------------------------------------------------------------
#define XROW 528   // bytes per LDS row (512 + 16 pad)

__device__ inline void stage_xt_tile(const short* __restrict__ src_base,
                                     char* __restrict__ sX, int t)
{
    const short* src = src_base + (size_t)(t >> 3) * 256 + (t & 7) * 32;
    char* dst = sX + (t >> 3) * XROW + (t & 7) * 64;
#pragma unroll
    for (int rr = 0; rr < 2; ++rr) {
        const short* s = src + rr * 32 * 256;
        char* d = dst + rr * 32 * XROW;
        *(int4*)d        = *(const int4*)s;
        *(int4*)(d + 16) = *(const int4*)(s + 8);
        *(int4*)(d + 32) = *(const int4*)(s + 16);
        *(int4*)(d + 48) = *(const int4*)(s + 24);
    }
}

__global__ __launch_bounds__(256) void conv_qkv_mfma(
    const short* __restrict__ Wqk,   // [512][256] bf16
    const short* __restrict__ Wv,    // [256][256] bf16
    const float* __restrict__ bqk,   // [512]
    const float* __restrict__ bv,    // [256]
    const short* __restrict__ XT,    // [B][NPIX][256] bf16
    short* __restrict__ QT,          // [B*8][NPIX][32]
    short* __restrict__ KT,          // [B*8][NPIX][32]
    short* __restrict__ VB)          // [B][256][NPIX]
{
    __shared__ __align__(16) char sX[64 * XROW];
    // ---- XCD-affinity decode: grid 864 = 8 xcd * 18 tl * 6 yy ----
    const int xcd = blockIdx.x & 7;
    const int loc = blockIdx.x >> 3;      // 0..107
    const int yy  = loc % 6;
    const int T   = (loc / 6) * 8 + xcd;  // tile id 0..143, T%8 == xcd
    const int n0  = (T % 36) * 64;
    const int b   = T / 36;

    const int t = threadIdx.x, lane = t & 63, w = t >> 6;
    const int l15 = lane & 15, quad = lane >> 4;

    stage_xt_tile(XT + ((size_t)b * NPIX + n0) * 256, sX, t);
    __syncthreads();

    floatx4 accs[2][4];
#pragma unroll
    for (int g = 0; g < 2; ++g) {
        const int og = yy + g * 6;
        const bool isV = (og >= 8);
        const short* Wb = isV ? Wv + (size_t)((og - 8) * 64 + w * 16 + l15) * CDIM
                              : Wqk + (size_t)(og * 64 + w * 16 + l15) * CDIM;
#pragma unroll
        for (int ib = 0; ib < 4; ++ib) accs[g][ib] = (floatx4){0.f, 0.f, 0.f, 0.f};
#pragma unroll
        for (int s = 0; s < 8; ++s) {
            short8v af = *(const short8v*)(Wb + s * 32 + quad * 8);
#pragma unroll
            for (int ib = 0; ib < 4; ++ib) {
                short8v bf = *(const short8v*)(sX + (ib * 16 + l15) * XROW + s * 64 + quad * 16);
                accs[g][ib] = __builtin_amdgcn_mfma_f32_16x16x32_bf16(af, bf, accs[g][ib], 0, 0, 0);
            }
        }
    }

#pragma unroll
    for (int g = 0; g < 2; ++g) {
        const int og = yy + g * 6;
        const bool isV = (og >= 8);
        __syncthreads();   // sX free (MFMA reads / prior store-reads done)
        if (!isV) {
            const bool isQ = (w < 2);
            const float scl = isQ ? SCALE_CONST * LOG2E : 1.0f;
            float bvv[4];
#pragma unroll
            for (int r = 0; r < 4; ++r) bvv[r] = bqk[og * 64 + w * 16 + quad * 4 + r];
#pragma unroll
            for (int ib = 0; ib < 4; ++ib) {
                short pb[4];
#pragma unroll
                for (int r = 0; r < 4; ++r) pb[r] = f2bf((accs[g][ib][r] + bvv[r]) * scl);
                *(short4v*)(sX + (ib * 16 + l15) * 136 + (w * 16 + quad * 4) * 2) = *(short4v*)pb;
            }
            __syncthreads();
            const int n = t >> 2, q = t & 3;
            int4 v0 = *(const int4*)(sX + n * 136 + q * 32);
            int4 v1 = *(const int4*)(sX + n * 136 + q * 32 + 16);
            short* dst = ((q < 2) ? QT : KT)
                       + ((size_t)(b * 8 + og) * NPIX + n0 + n) * HD + (q & 1) * 16;
            *(int4*)dst = v0;
            *(int4*)(dst + 8) = v1;
        } else {
            const int o0 = (og - 8) * 64 + w * 16 + quad * 4;
            float bvv[4];
#pragma unroll
            for (int r = 0; r < 4; ++r) bvv[r] = bv[o0 + r];
#pragma unroll
            for (int ib = 0; ib < 4; ++ib) {
                short pb[4];
#pragma unroll
                for (int r = 0; r < 4; ++r) pb[r] = f2bf(accs[g][ib][r] + bvv[r]);
                *(short4v*)(sX + (ib * 16 + l15) * 132 + (w * 16 + quad * 4) * 2) = *(short4v*)pb;
            }
            __syncthreads();
            const int o = t >> 2, q = t & 3;
            short tmp[16];
#pragma unroll
            for (int k = 0; k < 16; ++k)
                tmp[k] = *(const short*)(sX + (q * 16 + k) * 132 + o * 2);
            short* dst = VB + ((size_t)b * 256 + (og - 8) * 64 + o) * NPIX + n0 + q * 16;
            *(int4*)dst = *(int4*)tmp;
            *(int4*)(dst + 8) = *(int4*)(tmp + 8);
        }
    }
}

// ---------------------------------------------------------------------------
// Flash attention + lean fused depthwise-3x3 PE epilogue (R11 body).
// XCD-aware 1-D grid: hh = blockIdx & 7 -> per-XCD KV working set 1.2MB.
// ---------------------------------------------------------------------------
#define KROW 72
#define VROW 136
#define PROW 136
#define SK0 0                    // 64*72 = 4608
#define SK1 4608
#define SV0 9216                 // 32*136 = 4352
#define SV1 13568
#define SP0 17920                // 4 waves * 16 * 136 = 8704
#define FL_SMEM 26624
#define DROW 170                 // halo row: 85 dwords (odd -> conflict-free)

__global__ __launch_bounds__(256) void flash_attn_mfma(
    const short* __restrict__ QT,   // [bh][i][32] bf16, scaled by SCALE*LOG2E
    const short* __restrict__ KT,   // [bh][j][32] bf16
    const short* __restrict__ VB,   // [b][256][NPIX] bf16
    const float* __restrict__ w_pe, // [256][9] fp32
    const float* __restrict__ b_pe, // [256]
    short* __restrict__ ST)         // [b][NPIX][256] bf16 (= attn/l + pe)^T
{
    __shared__ __align__(16) char smem[FL_SMEM];

    const int hh   = blockIdx.x & 7;          // head -> fixed XCD
    const int slot = blockIdx.x >> 3;         // 0..143
    const int b    = slot / 36;
    const int i0   = (slot % 36) * 64;
    const int bh   = b * 8 + hh;

    const short* KTp = KT + (size_t)bh * NPIX * HD;
    const short* Vp  = VB + (size_t)(b * 256 + hh * HD) * NPIX;

    const int t    = threadIdx.x;
    const int lane = t & 63;
    const int w    = t >> 6;
    const int l15  = lane & 15;
    const int quad = lane >> 4;

    const short8v qfrag = *(const short8v*)(
        QT + ((size_t)bh * NPIX + i0 + w * 16 + l15) * HD + quad * 8);

    short8v ones;
#pragma unroll
    for (int k = 0; k < 8; ++k) ones[k] = (short)0x3F80;   // bf16 1.0

    char* const sPw = smem + SP0 + w * (16 * PROW);

    floatx4 oacc[2], lacc;
    oacc[0] = (floatx4){0.f, 0.f, 0.f, 0.f};
    oacc[1] = (floatx4){0.f, 0.f, 0.f, 0.f};
    lacc    = (floatx4){0.f, 0.f, 0.f, 0.f};

    const short* ksrc = KTp + (size_t)(t >> 2) * HD + (t & 3) * 8;
    const short* vsrc = Vp + (size_t)(t >> 3) * NPIX + (t & 7) * 8;
    const int koff = (t >> 2) * KROW + (t & 3) * 16;
    const int voff = (t >> 3) * VROW + (t & 7) * 16;

    int4 kst = *(const int4*)ksrc;
    int4 vst = *(const int4*)vsrc;

    for (int it = 0; it < 36; ++it) {
        char* bufK = smem + ((it & 1) ? SK1 : SK0);
        char* bufV = smem + ((it & 1) ? SV1 : SV0);
        *(int2*)(bufK + koff)     = *(int2*)&kst;
        *(int2*)(bufK + koff + 8) = *((int2*)&kst + 1);
        *(int2*)(bufV + voff)     = *(int2*)&vst;
        *(int2*)(bufV + voff + 8) = *((int2*)&vst + 1);
        if (it + 1 < 36) {
            kst = *(const int4*)(ksrc + (size_t)(it + 1) * 64 * HD);
            vst = *(const int4*)(vsrc + (it + 1) * 64);
        }
        __syncthreads();

        // ---- S' = K Q^T ----
        floatx4 sacc[4];
#pragma unroll
        for (int jb = 0; jb < 4; ++jb) {
            const char* ka = bufK + (jb * 16 + l15) * KROW + quad * 16;
            short8v af;
            ((int2*)&af)[0] = *(const int2*)ka;
            ((int2*)&af)[1] = *(const int2*)(ka + 8);
            sacc[jb] = __builtin_amdgcn_mfma_f32_16x16x32_bf16(
                af, qfrag, (floatx4){0.f, 0.f, 0.f, 0.f}, 0, 0, 0);
        }

        // ---- exp2(s) raw, pack bf16 P via v_perm ----
#pragma unroll
        for (int jb = 0; jb < 4; ++jb) {
            unsigned tb[4];
#pragma unroll
            for (int r = 0; r < 4; ++r)
                tb[r] = __builtin_bit_cast(unsigned, fexp2(sacc[jb][r]));
            int2 pw;
            pw.x = (int)__builtin_amdgcn_perm(tb[1], tb[0], 0x07060302u);
            pw.y = (int)__builtin_amdgcn_perm(tb[3], tb[2], 0x07060302u);
            *(int2*)(sPw + l15 * PROW + jb * 32 + quad * 8) = pw;
        }

        // ---- PV: O += V P ; l += ones P (same-wave P, no barrier) ----
#pragma unroll
        for (int ks = 0; ks < 2; ++ks) {
            const char* pa = sPw + l15 * PROW + ks * 64 + quad * 16;
            short8v pf;
            ((int2*)&pf)[0] = *(const int2*)pa;
            ((int2*)&pf)[1] = *(const int2*)(pa + 8);
#pragma unroll
            for (int db = 0; db < 2; ++db) {
                const char* va = bufV + (db * 16 + l15) * VROW + ks * 64 + quad * 16;
                short8v vf;
                ((int2*)&vf)[0] = *(const int2*)va;
                ((int2*)&vf)[1] = *(const int2*)(va + 8);
                oacc[db] = __builtin_amdgcn_mfma_f32_16x16x32_bf16(vf, pf, oacc[db], 0, 0, 0);
            }
            lacc = __builtin_amdgcn_mfma_f32_16x16x32_bf16(ones, pf, lacc, 0, 0, 0);
        }
    }

    // ================= epilogue: fused depthwise-3x3 PE =================
    const float invl = 1.0f / lacc[0];
    __syncthreads();   // all waves past final P/V LDS reads; smem free

    short* const sO    = (short*)smem;            // [64 px][36 shorts] (72B rows)
    short* const sHalo = (short*)(smem + 4608);   // [32 ch][170 shorts]

    // O (attn/l) -> LDS bf16, MFMA C-layout -> [px][d]
    {
        const int il = w * 16 + l15;
#pragma unroll
        for (int db = 0; db < 2; ++db) {
            short ob[4];
#pragma unroll
            for (int r = 0; r < 4; ++r) ob[r] = f2bf(oacc[db][r] * invl);
            *(short4v*)(sO + il * 36 + db * 16 + quad * 4) = *(short4v*)ob;
        }
    }
    // VB halo: 32 ch x 168 px window [i0-52, i0+116), zero-filled off-plane
    for (int ch8 = t; ch8 < 672; ch8 += 256) {
        int ch = ch8 / 21, off = (ch8 % 21) * 8;
        int base = i0 - 52 + off;
        const short* src = VB + ((size_t)b * 256 + hh * HD + ch) * NPIX;
        short tmp[8];
        if (base >= 0 && base + 8 <= NPIX) {
            *(int4*)tmp = *(const int4*)(src + base);
        } else {
#pragma unroll
            for (int u = 0; u < 8; ++u) {
                int p = base + u;
                tmp[u] = (p >= 0 && p < NPIX) ? src[p] : (short)0;
            }
        }
        *(int4*)&sHalo[ch * DROW + off] = *(int4*)tmp;
    }
    __syncthreads();

    // one channel per lane: d = t&31 (9 weights/thread), 8 px each
    {
        const int d  = t & 31;
        const int pg = t >> 5;
        const int c  = hh * HD + d;
        float wv[9];
#pragma unroll
        for (int k = 0; k < 9; ++k) wv[k] = w_pe[c * 9 + k];
        const float bb = b_pe[c];
        const int px0  = i0 + pg * 8;
        const int col0 = px0 % HW;
        const short* sprow = &sHalo[d * DROW + 52 + pg * 8];
        short* stp = ST + ((size_t)b * NPIX + px0) * 256 + c;

#pragma unroll
        for (int u = 0; u < 8; ++u) {
            int colu = col0 + u; if (colu >= HW) colu -= HW;
            const bool okL = (colu != 0), okR = (colu != HW - 1);
            float a = bb;
#pragma unroll
            for (int dy = 0; dy < 3; ++dy) {
                int ci = u + (dy - 1) * HW;
                a += wv[dy * 3 + 1] * bf2f((unsigned short)sprow[ci]);
                if (okL) a += wv[dy * 3 + 0] * bf2f((unsigned short)sprow[ci - 1]);
                if (okR) a += wv[dy * 3 + 2] * bf2f((unsigned short)sprow[ci + 1]);
            }
            float o = bf2f((unsigned short)sO[(pg * 8 + u) * 36 + d]);
            stp[(size_t)u * 256] = f2bf(o + a);
        }
    }
}

// ---------------------------------------------------------------------------
// Proj conv (MFMA), 1-D grid 576 with XCD affinity: all 4 og-blocks of a
// pixel-tile land on one XCD (ST tile fetched into one L2).
// ---------------------------------------------------------------------------
__global__ __launch_bounds__(256) void conv_proj_mfma(
    const short* __restrict__ Wb,    // [256][256] bf16
    const float* __restrict__ bias,
    const short* __restrict__ ST,    // [B][NPIX][256] bf16
    float* __restrict__ out)
{
    __shared__ __align__(16) char sX[64 * XROW];
    // ---- XCD-affinity decode: grid 576 = 8 xcd * 18 tl * 4 og ----
    const int xcd = blockIdx.x & 7;
    const int loc = blockIdx.x >> 3;      // 0..71
    const int og  = loc % 4;
    const int T   = (loc / 4) * 8 + xcd;  // tile id 0..143
    const int n0  = (T % 36) * 64;
    const int b   = T / 36;

    const int t = threadIdx.x, lane = t & 63, w = t >> 6;
    const int l15 = lane & 15, quad = lane >> 4;

    stage_xt_tile(ST + ((size_t)b * NPIX + n0) * 256, sX, t);
    __syncthreads();

    const short* Arow = Wb + (size_t)(og * 64 + w * 16 + l15) * CDIM;
    floatx4 acc[4];
#pragma unroll
    for (int ib = 0; ib < 4; ++ib) acc[ib] = (floatx4){0.f, 0.f, 0.f, 0.f};
#pragma unroll
    for (int s = 0; s < 8; ++s) {
        short8v af = *(const short8v*)(Arow + s * 32 + quad * 8);
#pragma unroll
        for (int ib = 0; ib < 4; ++ib) {
            short8v bf = *(const short8v*)(sX + (ib * 16 + l15) * XROW + s * 64 + quad * 16);
            acc[ib] = __builtin_amdgcn_mfma_f32_16x16x32_bf16(af, bf, acc[ib], 0, 0, 0);
        }
    }
    __syncthreads();   // sX reusable: repack [o][64 n] fp32, rows 272B

    {
        float bvv[4];
#pragma unroll
        for (int r = 0; r < 4; ++r) bvv[r] = bias[og * 64 + w * 16 + quad * 4 + r];
        float* sRep = (float*)sX;
#pragma unroll
        for (int r = 0; r < 4; ++r)
#pragma unroll
            for (int ib = 0; ib < 4; ++ib)
                sRep[(w * 16 + quad * 4 + r) * 68 + ib * 16 + l15] = acc[ib][r] + bvv[r];
    }
    __syncthreads();

    const int o = t >> 2, q = t & 3;
    const float* src = (const float*)sX + o * 68 + q * 16;
    float* dst = out + ((size_t)b * 256 + og * 64 + o) * NPIX + n0 + q * 16;
#pragma unroll
    for (int k = 0; k < 4; ++k)
        *(int4*)(dst + k * 4) = *(const int4*)(src + k * 4);
}

// ---------------------------------------------------------------------------
extern "C" void kernel_launch(void* const* d_in, const int* in_sizes, int n_in,
                              void* d_out, int out_size, void* d_ws, size_t ws_size,
                              hipStream_t stream) {
    const float* x      = (const float*)d_in[0];
    const float* w_qk   = (const float*)d_in[1];
    const float* b_qk   = (const float*)d_in[2];
    const float* w_v    = (const float*)d_in[3];
    const float* b_v    = (const float*)d_in[4];
    const float* w_pe   = (const float*)d_in[5];
    const float* b_pe   = (const float*)d_in[6];
    const float* w_proj = (const float*)d_in[7];
    const float* b_proj = (const float*)d_in[8];
    float* out = (float*)d_out;

    char* wsb = (char*)d_ws;
    short* ws_xt  = (short*)wsb;  wsb += (size_t)4 * NPIX * 256 * 2;   // XT bf16
    short* ws_qt  = (short*)wsb;  wsb += (size_t)32 * NPIX * HD * 2;   // QT bf16
    short* ws_kt  = (short*)wsb;  wsb += (size_t)32 * NPIX * HD * 2;   // KT bf16
    short* ws_vb  = (short*)wsb;  wsb += (size_t)4 * 256 * NPIX * 2;   // VB bf16
    short* ws_st  = (short*)wsb;  wsb += (size_t)4 * NPIX * 256 * 2;   // ST bf16
    short* ws_wqk = (short*)wsb;  wsb += (size_t)512 * 256 * 2;
    short* ws_wv  = (short*)wsb;  wsb += (size_t)256 * 256 * 2;
    short* ws_wp  = (short*)wsb;  wsb += (size_t)256 * 256 * 2;

    prep_kernel<<<dim3(640), 256, 0, stream>>>(x, ws_xt, w_qk, w_v, w_proj,
                                               ws_wqk, ws_wv, ws_wp);
    conv_qkv_mfma<<<dim3(864), 256, 0, stream>>>(ws_wqk, ws_wv, b_qk, b_v,
                                                 ws_xt, ws_qt, ws_kt, ws_vb);
    flash_attn_mfma<<<dim3(1152), 256, 0, stream>>>(ws_qt, ws_kt, ws_vb,
                                                    w_pe, b_pe, ws_st);
    conv_proj_mfma<<<dim3(576), 256, 0, stream>>>(ws_wp, b_proj, ws_st, out);
}